// Round 3
// baseline (54.805 us; speedup 1.0000x reference)
//
#include <hip/hip_runtime.h>

constexpr int HW = 4096;   // 64*64
constexpr int CT = 31;     // time channels
constexpr int CZ = 32;     // hidden channels
constexpr int CP = 128;    // poi channels
constexpr int CO = 64;     // output channels

// One block = 256-pixel tile of one batch image.
// 512 threads = 8 waves; wave w owns output channels [8w, 8w+8).
// Stage 1 (per-pixel time MLP) runs on threads 0..255, result in LDS.
__global__ __launch_bounds__(512, 4)
void poi_fused2(const float* __restrict__ poi,
                const float* __restrict__ tin,
                const float* __restrict__ wm,
                const float* __restrict__ bm,
                const float* __restrict__ wf,
                const float* __restrict__ bf,
                const float* __restrict__ wc,
                const float* __restrict__ bc,
                float* __restrict__ out)
{
    __shared__ float s_t[256];

    const int tid = threadIdx.x;
    const int b   = blockIdx.x >> 4;           // 16 tiles per image
    const int px0 = (blockIdx.x & 15) << 8;    // tile base pixel

    // ---- stage 1: t = relu(wf . relu(wm@time + bm) + bf), one px per thread ----
    if (tid < 256) {
        const float* tp = tin + (size_t)b * CT * HW + px0 + tid;
        float tr[CT];
        #pragma unroll
        for (int c = 0; c < CT; ++c) tr[c] = tp[(size_t)c * HW];   // coalesced
        float acc = bf[0];
        #pragma unroll
        for (int k = 0; k < CZ; ++k) {
            float z = bm[k];                                       // uniform s_load
            #pragma unroll
            for (int c = 0; c < CT; ++c)
                z = fmaf(wm[k * CT + c], tr[c], z);                // uniform s_load
            acc = fmaf(wf[k], fmaxf(z, 0.f), acc);
        }
        s_t[tid] = fmaxf(acc, 0.f);
    }
    __syncthreads();

    // ---- stage 2: out[o,px] = t[px] * (wc[o,:] . poi[:,px]) + bc[o] ----
    const int lane = tid & 63;
    const int og   = __builtin_amdgcn_readfirstlane(tid >> 6) * 8; // SGPR o-base
    const int px   = px0 + lane * 4;                               // 4 px per lane

    const float* pp = poi + (size_t)b * CP * HW + px;
    const float* wg = wc + (size_t)og * CP;                        // uniform base

    float4 acc[8];
    #pragma unroll
    for (int o = 0; o < 8; ++o) acc[o] = make_float4(0.f, 0.f, 0.f, 0.f);

    #pragma unroll 8
    for (int c = 0; c < CP; ++c) {
        const float4 p = *reinterpret_cast<const float4*>(pp + (size_t)c * HW);
        #pragma unroll
        for (int o = 0; o < 8; ++o) {
            const float w = wg[o * CP + c];                        // s_load_dwordx8
            acc[o].x = fmaf(w, p.x, acc[o].x);
            acc[o].y = fmaf(w, p.y, acc[o].y);
            acc[o].z = fmaf(w, p.z, acc[o].z);
            acc[o].w = fmaf(w, p.w, acc[o].w);
        }
    }

    const float4 tv = *reinterpret_cast<const float4*>(&s_t[lane * 4]);

    float* op = out + (size_t)b * CO * HW + (size_t)og * HW + px;
    #pragma unroll
    for (int o = 0; o < 8; ++o) {
        const float bias = bc[og + o];                             // uniform s_load
        float4 r;
        r.x = fmaf(tv.x, acc[o].x, bias);
        r.y = fmaf(tv.y, acc[o].y, bias);
        r.z = fmaf(tv.z, acc[o].z, bias);
        r.w = fmaf(tv.w, acc[o].w, bias);
        *reinterpret_cast<float4*>(op + (size_t)o * HW) = r;       // coalesced 1 KiB
    }
}

extern "C" void kernel_launch(void* const* d_in, const int* in_sizes, int n_in,
                              void* d_out, int out_size, void* d_ws, size_t ws_size,
                              hipStream_t stream) {
    const float* poi = (const float*)d_in[0];
    const float* tin = (const float*)d_in[1];
    const float* wm  = (const float*)d_in[2];
    const float* bm  = (const float*)d_in[3];
    const float* wf  = (const float*)d_in[4];
    const float* bf  = (const float*)d_in[5];
    const float* wc  = (const float*)d_in[6];
    const float* bc  = (const float*)d_in[7];
    float* out = (float*)d_out;

    // 32 images x 16 tiles = 512 blocks of 512 threads
    hipLaunchKernelGGL(poi_fused2, dim3(512), dim3(512), 0, stream,
                       poi, tin, wm, bm, wf, bf, wc, bc, out);
}